// Round 4
// baseline (3495.347 us; speedup 1.0000x reference)
//
#include <hip/hip_runtime.h>

// TransformerBlock: B=4 S=2048 D=1024 H=16 DK=64 DFF=4096
// inputs fp32, OUTPUT fp32 (reference dtype). GEMMs via mfma_f32_16x16x32_bf16.

typedef unsigned short ushort;
typedef __attribute__((ext_vector_type(8))) short bf16x8;
typedef __attribute__((ext_vector_type(4))) float f32x4;
typedef __attribute__((ext_vector_type(4))) unsigned short ushort4v;

#define B_ 4
#define S_ 2048
#define D_ 1024
#define H_ 16
#define DK_ 64
#define DFF_ 4096

__device__ __forceinline__ float b2f(ushort u){
  union { unsigned int i; float f; } x; x.i = ((unsigned int)u) << 16; return x.f;
}
__device__ __forceinline__ ushort f2b(float f){
  union { float f; unsigned int i; } x; x.f = f;
  return (ushort)((x.i + 0x7fffu + ((x.i >> 16) & 1u)) >> 16);
}

__device__ __forceinline__ f32x4 mfma16(bf16x8 a, bf16x8 b, f32x4 c){
  return __builtin_amdgcn_mfma_f32_16x16x32_bf16(a, b, c, 0, 0, 0);
}

// ---------------- transpose + fp32->bf16 convert: in[K][N] -> out[N][K] ----
__global__ void transpose_f32_bf16(const float* __restrict__ in,
                                   ushort* __restrict__ out, int K, int N){
  __shared__ ushort t[32][33];
  int k0 = blockIdx.y * 32, n0 = blockIdx.x * 32;
  for (int i = threadIdx.y; i < 32; i += 8)
    t[i][threadIdx.x] = f2b(in[(size_t)(k0 + i) * N + n0 + threadIdx.x]);
  __syncthreads();
  for (int i = threadIdx.y; i < 32; i += 8)
    out[(size_t)(n0 + i) * K + k0 + threadIdx.x] = t[threadIdx.x][i];
}

// ---------------- layernorm (fp32 in) -> bf16 out, one block per row ------
__global__ __launch_bounds__(256) void ln_f32(
    const float* __restrict__ x, const float* __restrict__ g,
    const float* __restrict__ be, ushort* __restrict__ out){
  int row = blockIdx.x; int t = threadIdx.x;
  const float* xr = x + (size_t)row * D_;
  float4 v = *(const float4*)(xr + t * 4);
  float s = v.x + v.y + v.z + v.w;
  float q = v.x*v.x + v.y*v.y + v.z*v.z + v.w*v.w;
  for (int off = 32; off; off >>= 1){
    s += __shfl_down(s, off);
    q += __shfl_down(q, off);
  }
  __shared__ float ss[4], sq[4];
  int wave = t >> 6, lane = t & 63;
  if (lane == 0){ ss[wave] = s; sq[wave] = q; }
  __syncthreads();
  float ts = ss[0] + ss[1] + ss[2] + ss[3];
  float tq = sq[0] + sq[1] + sq[2] + sq[3];
  float mu  = ts * (1.0f / D_);
  float var = tq * (1.0f / D_) - mu * mu;
  float rstd = rsqrtf(var + 1e-5f);
  float4 gv = *(const float4*)(g  + t * 4);
  float4 bv = *(const float4*)(be + t * 4);
  ushort4v o;
  o[0] = f2b((v.x - mu) * rstd * gv.x + bv.x);
  o[1] = f2b((v.y - mu) * rstd * gv.y + bv.y);
  o[2] = f2b((v.z - mu) * rstd * gv.z + bv.z);
  o[3] = f2b((v.w - mu) * rstd * gv.w + bv.w);
  *(ushort4v*)(out + (size_t)row * D_ + t * 4) = o;
}

// ---------------- GEMM: C = A[M,K](bf16) @ Bt[N,K]^T (bf16), fp32 acc -----
// 128x128 tile, BK=32, 4 waves (2x2), each wave 64x64 via 4x4 MFMA frags.
// MODE: 0 = bf16 store (plain)
//       1 = fp32 store: acc + bias + fp32 residual
//       2 = bf16 store: gelu(acc + bias)
template<int MODE>
__global__ __launch_bounds__(256) void gemm_bf16(
    const ushort* __restrict__ A, const ushort* __restrict__ Bt,
    void* __restrict__ Cv, const float* __restrict__ bias,
    const float* __restrict__ resf, int M, int N, int K)
{
  __shared__ ushort As[128 * 32];
  __shared__ ushort Bs[128 * 32];
  int m0 = blockIdx.y * 128, n0 = blockIdx.x * 128;
  int t = threadIdx.x;
  int sr = t >> 2, sc = (t & 3) << 3;
  int wv = t >> 6, lane = t & 63;
  int wr = wv >> 1, wc = wv & 1;
  int lg = lane >> 4, lr = lane & 15;

  f32x4 acc[4][4];
  for (int i = 0; i < 4; i++)
    for (int j = 0; j < 4; j++) acc[i][j] = (f32x4){0.f, 0.f, 0.f, 0.f};

  int nkt = K >> 5;
  for (int kt = 0; kt < nkt; ++kt){
    __syncthreads();
    const ushort* Ag = A  + (size_t)(m0 + sr) * K + (kt << 5) + sc;
    const ushort* Bg = Bt + (size_t)(n0 + sr) * K + (kt << 5) + sc;
    *(bf16x8*)(As + sr * 32 + sc)        = *(const bf16x8*)(Ag);
    *(bf16x8*)(As + (sr + 64) * 32 + sc) = *(const bf16x8*)(Ag + (size_t)64 * K);
    *(bf16x8*)(Bs + sr * 32 + sc)        = *(const bf16x8*)(Bg);
    *(bf16x8*)(Bs + (sr + 64) * 32 + sc) = *(const bf16x8*)(Bg + (size_t)64 * K);
    __syncthreads();
    bf16x8 af[4], bfr[4];
    for (int i = 0; i < 4; i++)
      af[i]  = *(const bf16x8*)(As + (wr * 64 + i * 16 + lr) * 32 + lg * 8);
    for (int j = 0; j < 4; j++)
      bfr[j] = *(const bf16x8*)(Bs + (wc * 64 + j * 16 + lr) * 32 + lg * 8);
    for (int i = 0; i < 4; i++)
      for (int j = 0; j < 4; j++)
        acc[i][j] = mfma16(af[i], bfr[j], acc[i][j]);
  }

  for (int i = 0; i < 4; i++){
    int mb = m0 + wr * 64 + i * 16 + lg * 4;
    for (int j = 0; j < 4; j++){
      int ng = n0 + wc * 64 + j * 16 + lr;
      for (int r = 0; r < 4; r++){
        int mg = mb + r;
        float vacc = acc[i][j][r];
        size_t idx = (size_t)mg * N + ng;
        if constexpr (MODE == 0){
          ((ushort*)Cv)[idx] = f2b(vacc);
        } else if constexpr (MODE == 1){
          ((float*)Cv)[idx] = vacc + bias[ng] + resf[idx];
        } else {
          float xv = vacc + bias[ng];
          float gel = xv * 0.5f * (1.0f + erff(xv * 0.70710678118f));
          ((ushort*)Cv)[idx] = f2b(gel);
        }
      }
    }
  }
}

// ---------------- naive causal attention, fp32 online softmax -------------
// grid (S/128, H, B), 128 threads; thread t owns q-row q0+t for head (b,h).
// q,k,v,out all [B*S][D] row-major bf16 (head slice at col h*64).
__global__ __launch_bounds__(128) void attn_naive(
    const ushort* __restrict__ qg, const ushort* __restrict__ kg,
    const ushort* __restrict__ vg, ushort* __restrict__ og)
{
  int hh = blockIdx.y, b = blockIdx.z;
  int q0 = blockIdx.x * 128;
  int t = threadIdx.x;
  int myq = q0 + t;
  __shared__ ushort Ks[64][64];
  __shared__ ushort Vs[64][64];

  const ushort* qrow = qg + ((size_t)b * S_ + myq) * D_ + hh * 64;
  float qf[64];
#pragma unroll
  for (int d8 = 0; d8 < 8; d8++){
    bf16x8 qv = *(const bf16x8*)(qrow + d8 * 8);
#pragma unroll
    for (int j = 0; j < 8; j++) qf[d8 * 8 + j] = b2f((ushort)qv[j]);
  }
  float m = -3.0e38f, l = 0.f;
  float out[64];
#pragma unroll
  for (int d = 0; d < 64; d++) out[d] = 0.f;

  int nkt = q0 / 64 + 2;
  for (int kt = 0; kt < nkt; kt++){
    int kb = kt * 64;
    __syncthreads();
    {
      int r = t >> 1, ch = (t & 1) * 32;
      const ushort* krow = kg + ((size_t)b * S_ + kb + r) * D_ + hh * 64 + ch;
      const ushort* vrow = vg + ((size_t)b * S_ + kb + r) * D_ + hh * 64 + ch;
#pragma unroll
      for (int u = 0; u < 4; u++){
        *(bf16x8*)&Ks[r][ch + u * 8] = *(const bf16x8*)(krow + u * 8);
        *(bf16x8*)&Vs[r][ch + u * 8] = *(const bf16x8*)(vrow + u * 8);
      }
    }
    __syncthreads();
    int kmax = myq - kb;
    if (kmax > 63) kmax = 63;
    for (int kk = 0; kk <= kmax; kk++){
      float s = 0.f;
#pragma unroll
      for (int d8 = 0; d8 < 8; d8++){
        bf16x8 kv = *(const bf16x8*)&Ks[kk][d8 * 8];
#pragma unroll
        for (int j = 0; j < 8; j++) s += qf[d8 * 8 + j] * b2f((ushort)kv[j]);
      }
      s *= 0.125f;                       // 1/sqrt(64)
      if (s > m){
        float alpha = expf(m - s);
        l *= alpha;
#pragma unroll
        for (int d = 0; d < 64; d++) out[d] *= alpha;
        m = s;
      }
      float p = expf(s - m);
      l += p;
#pragma unroll
      for (int d8 = 0; d8 < 8; d8++){
        bf16x8 vv = *(const bf16x8*)&Vs[kk][d8 * 8];
#pragma unroll
        for (int j = 0; j < 8; j++) out[d8 * 8 + j] += p * b2f((ushort)vv[j]);
      }
    }
  }
  ushort* orow = og + ((size_t)b * S_ + myq) * D_ + hh * 64;
  float inv = 1.0f / l;
#pragma unroll
  for (int d = 0; d < 64; d++) orow[d] = f2b(out[d] * inv);
}

// --------------------------------------------------------------------------
extern "C" void kernel_launch(void* const* d_in, const int* in_sizes, int n_in,
                              void* d_out, int out_size, void* d_ws, size_t ws_size,
                              hipStream_t stream)
{
  const float* x   = (const float*)d_in[0];
  const float* wq  = (const float*)d_in[1];
  const float* wk  = (const float*)d_in[2];
  const float* wv  = (const float*)d_in[3];
  const float* wo  = (const float*)d_in[4];
  const float* bo  = (const float*)d_in[5];
  const float* w1  = (const float*)d_in[6];
  const float* b1  = (const float*)d_in[7];
  const float* w2  = (const float*)d_in[8];
  const float* b2  = (const float*)d_in[9];
  const float* g1  = (const float*)d_in[10];
  const float* be1 = (const float*)d_in[11];
  const float* g2  = (const float*)d_in[12];
  const float* be2 = (const float*)d_in[13];

  char* ws = (char*)d_ws;
  const size_t MB = 1ull << 20;
  ushort* wqT  = (ushort*)(ws + 0 * MB);   // 2 MiB  [1024][1024]
  ushort* wkT  = (ushort*)(ws + 2 * MB);   // 2 MiB
  ushort* wvT  = (ushort*)(ws + 4 * MB);   // 2 MiB
  ushort* woT  = (ushort*)(ws + 6 * MB);   // 2 MiB
  ushort* w1T  = (ushort*)(ws + 8 * MB);   // 8 MiB  [4096][1024]
  ushort* w2T  = (ushort*)(ws + 16 * MB);  // 8 MiB  [1024][4096]
  ushort* hbuf = (ushort*)(ws + 24 * MB);  // 16 MiB: LN1 out -> attn out
  ushort* qbuf = (ushort*)(ws + 40 * MB);  // 16 MiB: Q
  ushort* kbuf = (ushort*)(ws + 56 * MB);  // 16 MiB: K -> h2 (LN2 out)
  ushort* vbuf = (ushort*)(ws + 72 * MB);  // 16 MiB: V -> ff1-chunk
  float*  x2f  = (float*)(ws + 88 * MB);   // 32 MiB: post-attn residual (fp32)
  // total 120 MiB

  dim3 tb(32, 8);
  transpose_f32_bf16<<<dim3(32, 32), tb, 0, stream>>>(wq, wqT, 1024, 1024);
  transpose_f32_bf16<<<dim3(32, 32), tb, 0, stream>>>(wk, wkT, 1024, 1024);
  transpose_f32_bf16<<<dim3(32, 32), tb, 0, stream>>>(wv, wvT, 1024, 1024);
  transpose_f32_bf16<<<dim3(32, 32), tb, 0, stream>>>(wo, woT, 1024, 1024);
  transpose_f32_bf16<<<dim3(128, 32), tb, 0, stream>>>(w1, w1T, 1024, 4096);
  transpose_f32_bf16<<<dim3(32, 128), tb, 0, stream>>>(w2, w2T, 4096, 1024);

  ln_f32<<<8192, 256, 0, stream>>>(x, g1, be1, hbuf);

  gemm_bf16<0><<<dim3(8, 64), 256, 0, stream>>>(hbuf, wqT, qbuf, nullptr, nullptr, 8192, 1024, 1024);
  gemm_bf16<0><<<dim3(8, 64), 256, 0, stream>>>(hbuf, wkT, kbuf, nullptr, nullptr, 8192, 1024, 1024);
  gemm_bf16<0><<<dim3(8, 64), 256, 0, stream>>>(hbuf, wvT, vbuf, nullptr, nullptr, 8192, 1024, 1024);

  attn_naive<<<dim3(16, 16, 4), 128, 0, stream>>>(qbuf, kbuf, vbuf, hbuf);  // hbuf = attn out

  // x2 = attn@wo + bo + x   (fp32)
  gemm_bf16<1><<<dim3(8, 64), 256, 0, stream>>>(hbuf, woT, x2f, bo, x, 8192, 1024, 1024);

  ln_f32<<<8192, 256, 0, stream>>>(x2f, g2, be2, kbuf);  // h2 into kbuf

  // feedforward in 4 row-chunks of 2048; ff1 output reuses vbuf (16 MiB)
  for (int c = 0; c < 4; ++c){
    const ushort* h2c = kbuf + (size_t)c * 2048 * 1024;
    float* outc = (float*)d_out + (size_t)c * 2048 * 1024;
    const float* x2c = x2f + (size_t)c * 2048 * 1024;
    gemm_bf16<2><<<dim3(32, 16), 256, 0, stream>>>(h2c, w1T, vbuf, b1, nullptr, 2048, 4096, 1024);
    gemm_bf16<1><<<dim3(8, 16), 256, 0, stream>>>(vbuf, w2T, outc, b2, x2c, 2048, 1024, 4096);
  }
}

// Round 5
// 1747.734 us; speedup vs baseline: 1.9999x; 1.9999x over previous
//
#include <hip/hip_runtime.h>

// TransformerBlock: B=4 S=2048 D=1024 H=16 DK=64 DFF=4096
// inputs fp32, OUTPUT fp32. GEMMs + flash attention via mfma_f32_16x16x32_bf16.

typedef unsigned short ushort;
typedef __attribute__((ext_vector_type(8))) short bf16x8;
typedef __attribute__((ext_vector_type(4))) float f32x4;
typedef __attribute__((ext_vector_type(4))) unsigned short ushort4v;

#define B_ 4
#define S_ 2048
#define D_ 1024
#define H_ 16
#define DK_ 64
#define DFF_ 4096

__device__ __forceinline__ float b2f(ushort u){
  union { unsigned int i; float f; } x; x.i = ((unsigned int)u) << 16; return x.f;
}
__device__ __forceinline__ ushort f2b(float f){
  union { float f; unsigned int i; } x; x.f = f;
  return (ushort)((x.i + 0x7fffu + ((x.i >> 16) & 1u)) >> 16);
}

__device__ __forceinline__ f32x4 mfma16(bf16x8 a, bf16x8 b, f32x4 c){
  return __builtin_amdgcn_mfma_f32_16x16x32_bf16(a, b, c, 0, 0, 0);
}

// ---------------- transpose + fp32->bf16 convert: in[K][N] -> out[N][K] ----
__global__ void transpose_f32_bf16(const float* __restrict__ in,
                                   ushort* __restrict__ out, int K, int N){
  __shared__ ushort t[32][33];
  int k0 = blockIdx.y * 32, n0 = blockIdx.x * 32;
  for (int i = threadIdx.y; i < 32; i += 8)
    t[i][threadIdx.x] = f2b(in[(size_t)(k0 + i) * N + n0 + threadIdx.x]);
  __syncthreads();
  for (int i = threadIdx.y; i < 32; i += 8)
    out[(size_t)(n0 + i) * K + k0 + threadIdx.x] = t[threadIdx.x][i];
}

// ---------------- layernorm (fp32 in) -> bf16 out, one block per row ------
__global__ __launch_bounds__(256) void ln_f32(
    const float* __restrict__ x, const float* __restrict__ g,
    const float* __restrict__ be, ushort* __restrict__ out){
  int row = blockIdx.x; int t = threadIdx.x;
  const float* xr = x + (size_t)row * D_;
  float4 v = *(const float4*)(xr + t * 4);
  float s = v.x + v.y + v.z + v.w;
  float q = v.x*v.x + v.y*v.y + v.z*v.z + v.w*v.w;
  for (int off = 32; off; off >>= 1){
    s += __shfl_down(s, off);
    q += __shfl_down(q, off);
  }
  __shared__ float ss[4], sq[4];
  int wave = t >> 6, lane = t & 63;
  if (lane == 0){ ss[wave] = s; sq[wave] = q; }
  __syncthreads();
  float ts = ss[0] + ss[1] + ss[2] + ss[3];
  float tq = sq[0] + sq[1] + sq[2] + sq[3];
  float mu  = ts * (1.0f / D_);
  float var = tq * (1.0f / D_) - mu * mu;
  float rstd = rsqrtf(var + 1e-5f);
  float4 gv = *(const float4*)(g  + t * 4);
  float4 bv = *(const float4*)(be + t * 4);
  ushort4v o;
  o[0] = f2b((v.x - mu) * rstd * gv.x + bv.x);
  o[1] = f2b((v.y - mu) * rstd * gv.y + bv.y);
  o[2] = f2b((v.z - mu) * rstd * gv.z + bv.z);
  o[3] = f2b((v.w - mu) * rstd * gv.w + bv.w);
  *(ushort4v*)(out + (size_t)row * D_ + t * 4) = o;
}

// ---------------- GEMM: C = A[M,K](bf16) @ Bt[N,K]^T (bf16), fp32 acc -----
// 128x128 tile, BK=32, 4 waves (2x2), each wave 64x64 via 4x4 MFMA frags.
// MODE: 0 = scatter bf16 -> [B,H,S,DK]   (Q, K)
//       1 = scatter bf16 -> [B,H,DK,S]   (V transposed)
//       2 = fp32 store: acc + bias + fp32 residual
//       3 = bf16 store: gelu(acc + bias)
template<int MODE>
__global__ __launch_bounds__(256) void gemm_bf16(
    const ushort* __restrict__ A, const ushort* __restrict__ Bt,
    void* __restrict__ Cv, const float* __restrict__ bias,
    const float* __restrict__ resf, int M, int N, int K)
{
  __shared__ ushort As[128 * 32];
  __shared__ ushort Bs[128 * 32];
  int m0 = blockIdx.y * 128, n0 = blockIdx.x * 128;
  int t = threadIdx.x;
  int sr = t >> 2, sc = (t & 3) << 3;
  int wv = t >> 6, lane = t & 63;
  int wr = wv >> 1, wc = wv & 1;
  int lg = lane >> 4, lr = lane & 15;

  f32x4 acc[4][4];
  for (int i = 0; i < 4; i++)
    for (int j = 0; j < 4; j++) acc[i][j] = (f32x4){0.f, 0.f, 0.f, 0.f};

  int nkt = K >> 5;
  for (int kt = 0; kt < nkt; ++kt){
    __syncthreads();
    const ushort* Ag = A  + (size_t)(m0 + sr) * K + (kt << 5) + sc;
    const ushort* Bg = Bt + (size_t)(n0 + sr) * K + (kt << 5) + sc;
    *(bf16x8*)(As + sr * 32 + sc)        = *(const bf16x8*)(Ag);
    *(bf16x8*)(As + (sr + 64) * 32 + sc) = *(const bf16x8*)(Ag + (size_t)64 * K);
    *(bf16x8*)(Bs + sr * 32 + sc)        = *(const bf16x8*)(Bg);
    *(bf16x8*)(Bs + (sr + 64) * 32 + sc) = *(const bf16x8*)(Bg + (size_t)64 * K);
    __syncthreads();
    bf16x8 af[4], bfr[4];
    for (int i = 0; i < 4; i++)
      af[i]  = *(const bf16x8*)(As + (wr * 64 + i * 16 + lr) * 32 + lg * 8);
    for (int j = 0; j < 4; j++)
      bfr[j] = *(const bf16x8*)(Bs + (wc * 64 + j * 16 + lr) * 32 + lg * 8);
    for (int i = 0; i < 4; i++)
      for (int j = 0; j < 4; j++)
        acc[i][j] = mfma16(af[i], bfr[j], acc[i][j]);
  }

  for (int i = 0; i < 4; i++){
    int mb = m0 + wr * 64 + i * 16 + lg * 4;
    for (int j = 0; j < 4; j++){
      int ng = n0 + wc * 64 + j * 16 + lr;
      for (int r = 0; r < 4; r++){
        int mg = mb + r;
        float vacc = acc[i][j][r];
        if constexpr (MODE == 0){
          int b = mg >> 11, si = mg & 2047;
          int hh = ng >> 6, dk = ng & 63;
          ((ushort*)Cv)[((((size_t)b * H_ + hh) * S_ + si) << 6) + dk] = f2b(vacc);
        } else if constexpr (MODE == 1){
          int b = mg >> 11, si = mg & 2047;
          int hh = ng >> 6, dk = ng & 63;
          ((ushort*)Cv)[((((size_t)b * H_ + hh) * DK_ + dk) << 11) + si] = f2b(vacc);
        } else if constexpr (MODE == 2){
          size_t idx = (size_t)mg * N + ng;
          ((float*)Cv)[idx] = vacc + bias[ng] + resf[idx];
        } else {
          size_t idx = (size_t)mg * N + ng;
          float xv = vacc + bias[ng];
          float gel = xv * 0.5f * (1.0f + erff(xv * 0.70710678118f));
          ((ushort*)Cv)[idx] = f2b(gel);
        }
      }
    }
  }
}

// ---------------- flash attention, causal, MFMA ---------------------------
// grid (S/64, H, B), 256 thr = 4 waves, each wave owns 16 q-rows.
// q,k: [B,H,S,DK] bf16; vT: [B,H,DK,S] bf16; out: [B*S, D] bf16 row-major.
__global__ __launch_bounds__(256) void attn_fwd(
    const ushort* __restrict__ qg, const ushort* __restrict__ kg,
    const ushort* __restrict__ vg, ushort* __restrict__ outp)
{
  int h = blockIdx.y, b = blockIdx.z;
  int wave = threadIdx.x >> 6, lane = threadIdx.x & 63;
  int lg = lane >> 4, lr = lane & 15;
  int qbase = blockIdx.x * 64 + wave * 16;
  const ushort* qp = qg + (((size_t)b * H_ + h) * S_) * DK_;
  const ushort* kp = kg + (((size_t)b * H_ + h) * S_) * DK_;
  const ushort* vp = vg + (((size_t)b * H_ + h) * DK_) * S_;
  __shared__ ushort plds[4][16][32];

  // Q fragments: lane lr = q-row, d = lg*8.. ; two frags cover d 0..63
  bf16x8 aq0 = *(const bf16x8*)(qp + (size_t)(qbase + lr) * DK_ + lg * 8);
  bf16x8 aq1 = *(const bf16x8*)(qp + (size_t)(qbase + lr) * DK_ + 32 + lg * 8);

  float m[4], l[4];
  f32x4 oacc[4];
  for (int r = 0; r < 4; r++){ m[r] = -3.0e38f; l[r] = 0.f; }
  for (int c = 0; c < 4; c++) oacc[c] = (f32x4){0.f, 0.f, 0.f, 0.f};

  int nkt = (qbase + 15) / 32 + 1;
  for (int kt = 0; kt < nkt; ++kt){
    int kb = kt * 32;
    f32x4 s[2];
    for (int kk = 0; kk < 2; kk++){
      bf16x8 bk0 = *(const bf16x8*)(kp + (size_t)(kb + kk * 16 + lr) * DK_ + lg * 8);
      bf16x8 bk1 = *(const bf16x8*)(kp + (size_t)(kb + kk * 16 + lr) * DK_ + 32 + lg * 8);
      f32x4 z = (f32x4){0.f, 0.f, 0.f, 0.f};
      s[kk] = mfma16(aq0, bk0, z);
      s[kk] = mfma16(aq1, bk1, s[kk]);
    }
    bool domask = (kb + 31) > qbase;
    for (int kk = 0; kk < 2; kk++)
      for (int r = 0; r < 4; r++){
        float sv = s[kk][r] * 0.125f;      // 1/sqrt(64)
        if (domask){
          int qgl = qbase + lg * 4 + r;     // D-layout row
          int kgl = kb + kk * 16 + lr;      // D-layout col
          if (kgl > qgl) sv = -1.0e30f;
        }
        s[kk][r] = sv;
      }
    float p0[4], p1[4], alpha[4];
    for (int r = 0; r < 4; r++){
      float rm = fmaxf(s[0][r], s[1][r]);
      for (int off = 1; off < 16; off <<= 1) rm = fmaxf(rm, __shfl_xor(rm, off));
      float mnew = fmaxf(m[r], rm);
      alpha[r] = expf(m[r] - mnew);
      p0[r] = expf(s[0][r] - mnew);
      p1[r] = expf(s[1][r] - mnew);
      float rs = p0[r] + p1[r];
      for (int off = 1; off < 16; off <<= 1) rs += __shfl_xor(rs, off);
      l[r] = l[r] * alpha[r] + rs;
      m[r] = mnew;
    }
    for (int c = 0; c < 4; c++)
      for (int r = 0; r < 4; r++) oacc[c][r] *= alpha[r];
    // P: D-layout (row=lg*4+r, col=lr) -> LDS -> A-layout fragment (same-wave)
    for (int r = 0; r < 4; r++){
      plds[wave][lg * 4 + r][lr]      = f2b(p0[r]);
      plds[wave][lg * 4 + r][16 + lr] = f2b(p1[r]);
    }
    bf16x8 pa = *(const bf16x8*)(&plds[wave][lr][lg * 8]);
    for (int c = 0; c < 4; c++){
      bf16x8 bv = *(const bf16x8*)(vp + (size_t)(c * 16 + lr) * S_ + kb + lg * 8);
      oacc[c] = mfma16(pa, bv, oacc[c]);
    }
  }
  for (int c = 0; c < 4; c++)
    for (int r = 0; r < 4; r++){
      size_t row = (size_t)b * S_ + qbase + lg * 4 + r;
      outp[row * D_ + h * DK_ + c * 16 + lr] = f2b(oacc[c][r] / l[r]);
    }
}

// --------------------------------------------------------------------------
extern "C" void kernel_launch(void* const* d_in, const int* in_sizes, int n_in,
                              void* d_out, int out_size, void* d_ws, size_t ws_size,
                              hipStream_t stream)
{
  const float* x   = (const float*)d_in[0];
  const float* wq  = (const float*)d_in[1];
  const float* wk  = (const float*)d_in[2];
  const float* wv  = (const float*)d_in[3];
  const float* wo  = (const float*)d_in[4];
  const float* bo  = (const float*)d_in[5];
  const float* w1  = (const float*)d_in[6];
  const float* b1  = (const float*)d_in[7];
  const float* w2  = (const float*)d_in[8];
  const float* b2  = (const float*)d_in[9];
  const float* g1  = (const float*)d_in[10];
  const float* be1 = (const float*)d_in[11];
  const float* g2  = (const float*)d_in[12];
  const float* be2 = (const float*)d_in[13];

  char* ws = (char*)d_ws;
  const size_t MB = 1ull << 20;
  ushort* wqT  = (ushort*)(ws + 0 * MB);   // 2 MiB  [1024][1024]
  ushort* wkT  = (ushort*)(ws + 2 * MB);   // 2 MiB
  ushort* wvT  = (ushort*)(ws + 4 * MB);   // 2 MiB
  ushort* woT  = (ushort*)(ws + 6 * MB);   // 2 MiB
  ushort* w1T  = (ushort*)(ws + 8 * MB);   // 8 MiB  [4096][1024]
  ushort* w2T  = (ushort*)(ws + 16 * MB);  // 8 MiB  [1024][4096]
  ushort* hbuf = (ushort*)(ws + 24 * MB);  // 16 MiB: LN1 out -> attn out
  ushort* qbuf = (ushort*)(ws + 40 * MB);  // 16 MiB: Q [B,H,S,DK]
  ushort* kbuf = (ushort*)(ws + 56 * MB);  // 16 MiB: K [B,H,S,DK] -> h2 (LN2 out)
  ushort* vbuf = (ushort*)(ws + 72 * MB);  // 16 MiB: V [B,H,DK,S] -> ff1-chunk
  float*  x2f  = (float*)(ws + 88 * MB);   // 32 MiB: post-attn residual (fp32)
  // total 120 MiB

  dim3 tb(32, 8);
  transpose_f32_bf16<<<dim3(32, 32), tb, 0, stream>>>(wq, wqT, 1024, 1024);
  transpose_f32_bf16<<<dim3(32, 32), tb, 0, stream>>>(wk, wkT, 1024, 1024);
  transpose_f32_bf16<<<dim3(32, 32), tb, 0, stream>>>(wv, wvT, 1024, 1024);
  transpose_f32_bf16<<<dim3(32, 32), tb, 0, stream>>>(wo, woT, 1024, 1024);
  transpose_f32_bf16<<<dim3(128, 32), tb, 0, stream>>>(w1, w1T, 1024, 4096);
  transpose_f32_bf16<<<dim3(32, 128), tb, 0, stream>>>(w2, w2T, 4096, 1024);

  ln_f32<<<8192, 256, 0, stream>>>(x, g1, be1, hbuf);

  gemm_bf16<0><<<dim3(8, 64), 256, 0, stream>>>(hbuf, wqT, qbuf, nullptr, nullptr, 8192, 1024, 1024);
  gemm_bf16<0><<<dim3(8, 64), 256, 0, stream>>>(hbuf, wkT, kbuf, nullptr, nullptr, 8192, 1024, 1024);
  gemm_bf16<1><<<dim3(8, 64), 256, 0, stream>>>(hbuf, wvT, vbuf, nullptr, nullptr, 8192, 1024, 1024);

  attn_fwd<<<dim3(32, 16, 4), 256, 0, stream>>>(qbuf, kbuf, vbuf, hbuf);  // hbuf = attn out

  // x2 = attn@wo + bo + x   (fp32)
  gemm_bf16<2><<<dim3(8, 64), 256, 0, stream>>>(hbuf, woT, x2f, bo, x, 8192, 1024, 1024);

  ln_f32<<<8192, 256, 0, stream>>>(x2f, g2, be2, kbuf);  // h2 into kbuf

  // feedforward in 4 row-chunks of 2048; ff1 output reuses vbuf (16 MiB)
  for (int c = 0; c < 4; ++c){
    const ushort* h2c = kbuf + (size_t)c * 2048 * 1024;
    float* outc = (float*)d_out + (size_t)c * 2048 * 1024;
    const float* x2c = x2f + (size_t)c * 2048 * 1024;
    gemm_bf16<3><<<dim3(32, 16), 256, 0, stream>>>(h2c, w1T, vbuf, b1, nullptr, 2048, 4096, 1024);
    gemm_bf16<2><<<dim3(8, 16), 256, 0, stream>>>(vbuf, w2T, outc, b2, x2c, 2048, 1024, 4096);
  }
}

// Round 6
// 1730.533 us; speedup vs baseline: 2.0198x; 1.0099x over previous
//
#include <hip/hip_runtime.h>

// TransformerBlock: B=4 S=2048 D=1024 H=16 DK=64 DFF=4096
// inputs fp32, OUTPUT fp32. GEMMs + flash attention via mfma_f32_16x16x32_bf16.
// GEMM staging via global_load_lds width=16 (m97 pattern).

typedef unsigned short ushort;
typedef __attribute__((ext_vector_type(8))) short bf16x8;
typedef __attribute__((ext_vector_type(4))) float f32x4;
typedef __attribute__((ext_vector_type(4))) unsigned short ushort4v;

#define B_ 4
#define S_ 2048
#define D_ 1024
#define H_ 16
#define DK_ 64
#define DFF_ 4096

__device__ __forceinline__ float b2f(ushort u){
  union { unsigned int i; float f; } x; x.i = ((unsigned int)u) << 16; return x.f;
}
__device__ __forceinline__ ushort f2b(float f){
  union { float f; unsigned int i; } x; x.f = f;
  return (ushort)((x.i + 0x7fffu + ((x.i >> 16) & 1u)) >> 16);
}

__device__ __forceinline__ f32x4 mfma16(bf16x8 a, bf16x8 b, f32x4 c){
  return __builtin_amdgcn_mfma_f32_16x16x32_bf16(a, b, c, 0, 0, 0);
}

// async global->LDS, 16B per lane; LDS dest = uniform base + lane*16
__device__ __forceinline__ void gload16(const ushort* g, ushort* l){
  __builtin_amdgcn_global_load_lds(
      (const __attribute__((address_space(1))) void*)g,
      (__attribute__((address_space(3))) void*)l, 16, 0, 0);
}

// ---------------- transpose + fp32->bf16 convert: in[K][N] -> out[N][K] ----
__global__ void transpose_f32_bf16(const float* __restrict__ in,
                                   ushort* __restrict__ out, int K, int N){
  __shared__ ushort t[32][33];
  int k0 = blockIdx.y * 32, n0 = blockIdx.x * 32;
  for (int i = threadIdx.y; i < 32; i += 8)
    t[i][threadIdx.x] = f2b(in[(size_t)(k0 + i) * N + n0 + threadIdx.x]);
  __syncthreads();
  for (int i = threadIdx.y; i < 32; i += 8)
    out[(size_t)(n0 + i) * K + k0 + threadIdx.x] = t[threadIdx.x][i];
}

// ---------------- layernorm (fp32 in) -> bf16 out, one block per row ------
__global__ __launch_bounds__(256) void ln_f32(
    const float* __restrict__ x, const float* __restrict__ g,
    const float* __restrict__ be, ushort* __restrict__ out){
  int row = blockIdx.x; int t = threadIdx.x;
  const float* xr = x + (size_t)row * D_;
  float4 v = *(const float4*)(xr + t * 4);
  float s = v.x + v.y + v.z + v.w;
  float q = v.x*v.x + v.y*v.y + v.z*v.z + v.w*v.w;
  for (int off = 32; off; off >>= 1){
    s += __shfl_down(s, off);
    q += __shfl_down(q, off);
  }
  __shared__ float ss[4], sq[4];
  int wave = t >> 6, lane = t & 63;
  if (lane == 0){ ss[wave] = s; sq[wave] = q; }
  __syncthreads();
  float ts = ss[0] + ss[1] + ss[2] + ss[3];
  float tq = sq[0] + sq[1] + sq[2] + sq[3];
  float mu  = ts * (1.0f / D_);
  float var = tq * (1.0f / D_) - mu * mu;
  float rstd = rsqrtf(var + 1e-5f);
  float4 gv = *(const float4*)(g  + t * 4);
  float4 bv = *(const float4*)(be + t * 4);
  ushort4v o;
  o[0] = f2b((v.x - mu) * rstd * gv.x + bv.x);
  o[1] = f2b((v.y - mu) * rstd * gv.y + bv.y);
  o[2] = f2b((v.z - mu) * rstd * gv.z + bv.z);
  o[3] = f2b((v.w - mu) * rstd * gv.w + bv.w);
  *(ushort4v*)(out + (size_t)row * D_ + t * 4) = o;
}

// ---------------- GEMM: C = A[M,K](bf16) @ Bt[N,K]^T (bf16), fp32 acc -----
// 128x128 tile, BK=32, 4 waves (2x2), each wave 64x64 via 4x4 MFMA frags.
// Staging: global_load_lds dwordx4; each wave issues 2 chunks for As, 2 for Bs.
// MODE: 0 = fused QKV scatter: C0=q[B,H,S,DK], C1=k[B,H,S,DK], C2=vT[B,H,DK,S]
//       1 = fp32 store: acc + bias + fp32 residual (C0)
//       2 = bf16 store: gelu(acc + bias) (C0)
template<int MODE>
__global__ __launch_bounds__(256) void gemm_bf16(
    const ushort* __restrict__ A, const ushort* __restrict__ Bt,
    void* __restrict__ C0, void* __restrict__ C1, void* __restrict__ C2,
    const float* __restrict__ bias, const float* __restrict__ resf,
    int M, int N, int K)
{
  __shared__ ushort As[128 * 32];
  __shared__ ushort Bs[128 * 32];
  int m0 = blockIdx.y * 128, n0 = blockIdx.x * 128;
  int t = threadIdx.x;
  int wv = t >> 6, lane = t & 63;
  int wr = wv >> 1, wc = wv & 1;
  int lg = lane >> 4, lr = lane & 15;
  int lrow = lane >> 2, lcol = (lane & 3) << 3;   // staging: 16 rows x 32 cols per chunk

  f32x4 acc[4][4];
  for (int i = 0; i < 4; i++)
    for (int j = 0; j < 4; j++) acc[i][j] = (f32x4){0.f, 0.f, 0.f, 0.f};

  int nkt = K >> 5;
  for (int kt = 0; kt < nkt; ++kt){
    __syncthreads();
    {
      const ushort* Ag = A  + (size_t)(m0 + wv * 16 + lrow) * K + (kt << 5) + lcol;
      const ushort* Bg = Bt + (size_t)(n0 + wv * 16 + lrow) * K + (kt << 5) + lcol;
      gload16(Ag,                    As + wv * 512);
      gload16(Ag + (size_t)64 * K,   As + 2048 + wv * 512);
      gload16(Bg,                    Bs + wv * 512);
      gload16(Bg + (size_t)64 * K,   Bs + 2048 + wv * 512);
    }
    __syncthreads();
    bf16x8 af[4], bfr[4];
    for (int i = 0; i < 4; i++)
      af[i]  = *(const bf16x8*)(As + (wr * 64 + i * 16 + lr) * 32 + lg * 8);
    for (int j = 0; j < 4; j++)
      bfr[j] = *(const bf16x8*)(Bs + (wc * 64 + j * 16 + lr) * 32 + lg * 8);
    for (int i = 0; i < 4; i++)
      for (int j = 0; j < 4; j++)
        acc[i][j] = mfma16(af[i], bfr[j], acc[i][j]);
  }

  for (int i = 0; i < 4; i++){
    int mb = m0 + wr * 64 + i * 16 + lg * 4;
    for (int j = 0; j < 4; j++){
      int ng = n0 + wc * 64 + j * 16 + lr;
      for (int r = 0; r < 4; r++){
        int mg = mb + r;
        float vacc = acc[i][j][r];
        if constexpr (MODE == 0){
          int b = mg >> 11, si = mg & 2047;
          int which = ng >> 10;
          int hh = (ng >> 6) & 15, dk = ng & 63;
          if (which == 0)
            ((ushort*)C0)[((((size_t)b * H_ + hh) * S_ + si) << 6) + dk] = f2b(vacc);
          else if (which == 1)
            ((ushort*)C1)[((((size_t)b * H_ + hh) * S_ + si) << 6) + dk] = f2b(vacc);
          else
            ((ushort*)C2)[((((size_t)b * H_ + hh) * DK_ + dk) << 11) + si] = f2b(vacc);
        } else if constexpr (MODE == 1){
          size_t idx = (size_t)mg * N + ng;
          ((float*)C0)[idx] = vacc + bias[ng] + resf[idx];
        } else {
          size_t idx = (size_t)mg * N + ng;
          float xv = vacc + bias[ng];
          float gel = xv * 0.5f * (1.0f + erff(xv * 0.70710678118f));
          ((ushort*)C0)[idx] = f2b(gel);
        }
      }
    }
  }
}

// ---------------- flash attention, causal, MFMA ---------------------------
// grid (S/64, H, B), 256 thr = 4 waves, each wave owns 16 q-rows.
// q,k: [B,H,S,DK] bf16; vT: [B,H,DK,S] bf16; out: [B*S, D] bf16 row-major.
__global__ __launch_bounds__(256) void attn_fwd(
    const ushort* __restrict__ qg, const ushort* __restrict__ kg,
    const ushort* __restrict__ vg, ushort* __restrict__ outp)
{
  int h = blockIdx.y, b = blockIdx.z;
  int wave = threadIdx.x >> 6, lane = threadIdx.x & 63;
  int lg = lane >> 4, lr = lane & 15;
  int qbase = blockIdx.x * 64 + wave * 16;
  const ushort* qp = qg + (((size_t)b * H_ + h) * S_) * DK_;
  const ushort* kp = kg + (((size_t)b * H_ + h) * S_) * DK_;
  const ushort* vp = vg + (((size_t)b * H_ + h) * DK_) * S_;
  __shared__ ushort plds[4][16][32];

  bf16x8 aq0 = *(const bf16x8*)(qp + (size_t)(qbase + lr) * DK_ + lg * 8);
  bf16x8 aq1 = *(const bf16x8*)(qp + (size_t)(qbase + lr) * DK_ + 32 + lg * 8);

  float m[4], l[4];
  f32x4 oacc[4];
  for (int r = 0; r < 4; r++){ m[r] = -3.0e38f; l[r] = 0.f; }
  for (int c = 0; c < 4; c++) oacc[c] = (f32x4){0.f, 0.f, 0.f, 0.f};

  int nkt = (qbase + 15) / 32 + 1;
  for (int kt = 0; kt < nkt; ++kt){
    int kb = kt * 32;
    f32x4 s[2];
    for (int kk = 0; kk < 2; kk++){
      bf16x8 bk0 = *(const bf16x8*)(kp + (size_t)(kb + kk * 16 + lr) * DK_ + lg * 8);
      bf16x8 bk1 = *(const bf16x8*)(kp + (size_t)(kb + kk * 16 + lr) * DK_ + 32 + lg * 8);
      f32x4 z = (f32x4){0.f, 0.f, 0.f, 0.f};
      s[kk] = mfma16(aq0, bk0, z);
      s[kk] = mfma16(aq1, bk1, s[kk]);
    }
    bool domask = (kb + 31) > qbase;
    for (int kk = 0; kk < 2; kk++)
      for (int r = 0; r < 4; r++){
        float sv = s[kk][r] * 0.125f;      // 1/sqrt(64)
        if (domask){
          int qgl = qbase + lg * 4 + r;     // D-layout row
          int kgl = kb + kk * 16 + lr;      // D-layout col
          if (kgl > qgl) sv = -1.0e30f;
        }
        s[kk][r] = sv;
      }
    float p0[4], p1[4], alpha[4];
    for (int r = 0; r < 4; r++){
      float rm = fmaxf(s[0][r], s[1][r]);
      for (int off = 1; off < 16; off <<= 1) rm = fmaxf(rm, __shfl_xor(rm, off));
      float mnew = fmaxf(m[r], rm);
      alpha[r] = expf(m[r] - mnew);
      p0[r] = expf(s[0][r] - mnew);
      p1[r] = expf(s[1][r] - mnew);
      float rs = p0[r] + p1[r];
      for (int off = 1; off < 16; off <<= 1) rs += __shfl_xor(rs, off);
      l[r] = l[r] * alpha[r] + rs;
      m[r] = mnew;
    }
    for (int c = 0; c < 4; c++)
      for (int r = 0; r < 4; r++) oacc[c][r] *= alpha[r];
    for (int r = 0; r < 4; r++){
      plds[wave][lg * 4 + r][lr]      = f2b(p0[r]);
      plds[wave][lg * 4 + r][16 + lr] = f2b(p1[r]);
    }
    bf16x8 pa = *(const bf16x8*)(&plds[wave][lr][lg * 8]);
    for (int c = 0; c < 4; c++){
      bf16x8 bv = *(const bf16x8*)(vp + (size_t)(c * 16 + lr) * S_ + kb + lg * 8);
      oacc[c] = mfma16(pa, bv, oacc[c]);
    }
  }
  for (int c = 0; c < 4; c++)
    for (int r = 0; r < 4; r++){
      size_t row = (size_t)b * S_ + qbase + lg * 4 + r;
      outp[row * D_ + h * DK_ + c * 16 + lr] = f2b(oacc[c][r] / l[r]);
    }
}

// --------------------------------------------------------------------------
extern "C" void kernel_launch(void* const* d_in, const int* in_sizes, int n_in,
                              void* d_out, int out_size, void* d_ws, size_t ws_size,
                              hipStream_t stream)
{
  const float* x   = (const float*)d_in[0];
  const float* wq  = (const float*)d_in[1];
  const float* wk  = (const float*)d_in[2];
  const float* wv  = (const float*)d_in[3];
  const float* wo  = (const float*)d_in[4];
  const float* bo  = (const float*)d_in[5];
  const float* w1  = (const float*)d_in[6];
  const float* b1  = (const float*)d_in[7];
  const float* w2  = (const float*)d_in[8];
  const float* b2  = (const float*)d_in[9];
  const float* g1  = (const float*)d_in[10];
  const float* be1 = (const float*)d_in[11];
  const float* g2  = (const float*)d_in[12];
  const float* be2 = (const float*)d_in[13];

  char* ws = (char*)d_ws;
  const size_t MB = 1ull << 20;
  ushort* wqkvT = (ushort*)(ws + 0 * MB);  // 6 MiB [3072][1024]: wq^T|wk^T|wv^T
  ushort* woT  = (ushort*)(ws + 6 * MB);   // 2 MiB
  ushort* w1T  = (ushort*)(ws + 8 * MB);   // 8 MiB  [4096][1024]
  ushort* w2T  = (ushort*)(ws + 16 * MB);  // 8 MiB  [1024][4096]
  ushort* hbuf = (ushort*)(ws + 24 * MB);  // 16 MiB: LN1 out -> attn out
  ushort* qbuf = (ushort*)(ws + 40 * MB);  // 16 MiB: Q [B,H,S,DK]
  ushort* kbuf = (ushort*)(ws + 56 * MB);  // 16 MiB: K [B,H,S,DK] -> h2 (LN2 out)
  ushort* vbuf = (ushort*)(ws + 72 * MB);  // 16 MiB: V [B,H,DK,S] -> ff1-chunk
  float*  x2f  = (float*)(ws + 88 * MB);   // 32 MiB: post-attn residual (fp32)
  // total 120 MiB

  dim3 tb(32, 8);
  transpose_f32_bf16<<<dim3(32, 32), tb, 0, stream>>>(wq, wqkvT, 1024, 1024);
  transpose_f32_bf16<<<dim3(32, 32), tb, 0, stream>>>(wk, wqkvT + (1024ull*1024), 1024, 1024);
  transpose_f32_bf16<<<dim3(32, 32), tb, 0, stream>>>(wv, wqkvT + (2048ull*1024), 1024, 1024);
  transpose_f32_bf16<<<dim3(32, 32), tb, 0, stream>>>(wo, woT, 1024, 1024);
  transpose_f32_bf16<<<dim3(128, 32), tb, 0, stream>>>(w1, w1T, 1024, 4096);
  transpose_f32_bf16<<<dim3(32, 128), tb, 0, stream>>>(w2, w2T, 4096, 1024);

  ln_f32<<<8192, 256, 0, stream>>>(x, g1, be1, hbuf);

  // fused QKV: [8192,1024] @ [3072,1024]^T, scatter epilogue
  gemm_bf16<0><<<dim3(24, 64), 256, 0, stream>>>(hbuf, wqkvT, qbuf, kbuf, vbuf,
                                                 nullptr, nullptr, 8192, 3072, 1024);

  attn_fwd<<<dim3(32, 16, 4), 256, 0, stream>>>(qbuf, kbuf, vbuf, hbuf);  // hbuf = attn out

  // x2 = attn@wo + bo + x   (fp32)
  gemm_bf16<1><<<dim3(8, 64), 256, 0, stream>>>(hbuf, woT, x2f, nullptr, nullptr,
                                                bo, x, 8192, 1024, 1024);

  ln_f32<<<8192, 256, 0, stream>>>(x2f, g2, be2, kbuf);  // h2 into kbuf

  // feedforward in 4 row-chunks of 2048; ff1 output reuses vbuf (16 MiB)
  for (int c = 0; c < 4; ++c){
    const ushort* h2c = kbuf + (size_t)c * 2048 * 1024;
    float* outc = (float*)d_out + (size_t)c * 2048 * 1024;
    const float* x2c = x2f + (size_t)c * 2048 * 1024;
    gemm_bf16<2><<<dim3(32, 16), 256, 0, stream>>>(h2c, w1T, vbuf, nullptr, nullptr,
                                                   b1, nullptr, 2048, 4096, 1024);
    gemm_bf16<1><<<dim3(8, 16), 256, 0, stream>>>(vbuf, w2T, outc, nullptr, nullptr,
                                                  b2, x2c, 2048, 1024, 4096);
  }
}

// Round 7
// 1421.555 us; speedup vs baseline: 2.4588x; 1.2174x over previous
//
#include <hip/hip_runtime.h>

// TransformerBlock: B=4 S=2048 D=1024 H=16 DK=64 DFF=4096
// inputs fp32, OUTPUT fp32. GEMMs + flash attention via mfma_f32_16x16x32_bf16.

typedef unsigned short ushort;
typedef __attribute__((ext_vector_type(8))) short bf16x8;
typedef __attribute__((ext_vector_type(4))) float f32x4;
typedef __attribute__((ext_vector_type(4))) unsigned short ushort4v;

#define B_ 4
#define S_ 2048
#define D_ 1024
#define H_ 16
#define DK_ 64
#define DFF_ 4096

__device__ __forceinline__ float b2f(ushort u){
  union { unsigned int i; float f; } x; x.i = ((unsigned int)u) << 16; return x.f;
}
__device__ __forceinline__ ushort f2b(float f){
  union { float f; unsigned int i; } x; x.f = f;
  return (ushort)((x.i + 0x7fffu + ((x.i >> 16) & 1u)) >> 16);
}

__device__ __forceinline__ f32x4 mfma16(bf16x8 a, bf16x8 b, f32x4 c){
  return __builtin_amdgcn_mfma_f32_16x16x32_bf16(a, b, c, 0, 0, 0);
}

// async global->LDS, 16B per lane; LDS dest = wave-uniform base + lane*16
__device__ __forceinline__ void gload16(const ushort* g, ushort* l){
  __builtin_amdgcn_global_load_lds(
      (const __attribute__((address_space(1))) void*)g,
      (__attribute__((address_space(3))) void*)l, 16, 0, 0);
}

// ---------------- transpose + fp32->bf16 convert: in[K][N] -> out[N][K] ----
__global__ void transpose_f32_bf16(const float* __restrict__ in,
                                   ushort* __restrict__ out, int K, int N){
  __shared__ ushort t[32][33];
  int k0 = blockIdx.y * 32, n0 = blockIdx.x * 32;
  for (int i = threadIdx.y; i < 32; i += 8)
    t[i][threadIdx.x] = f2b(in[(size_t)(k0 + i) * N + n0 + threadIdx.x]);
  __syncthreads();
  for (int i = threadIdx.y; i < 32; i += 8)
    out[(size_t)(n0 + i) * K + k0 + threadIdx.x] = t[threadIdx.x][i];
}

// ---------------- layernorm (fp32 in) -> bf16 out, one block per row ------
__global__ __launch_bounds__(256) void ln_f32(
    const float* __restrict__ x, const float* __restrict__ g,
    const float* __restrict__ be, ushort* __restrict__ out){
  int row = blockIdx.x; int t = threadIdx.x;
  const float* xr = x + (size_t)row * D_;
  float4 v = *(const float4*)(xr + t * 4);
  float s = v.x + v.y + v.z + v.w;
  float q = v.x*v.x + v.y*v.y + v.z*v.z + v.w*v.w;
  for (int off = 32; off; off >>= 1){
    s += __shfl_down(s, off);
    q += __shfl_down(q, off);
  }
  __shared__ float ss[4], sq[4];
  int wave = t >> 6, lane = t & 63;
  if (lane == 0){ ss[wave] = s; sq[wave] = q; }
  __syncthreads();
  float ts = ss[0] + ss[1] + ss[2] + ss[3];
  float tq = sq[0] + sq[1] + sq[2] + sq[3];
  float mu  = ts * (1.0f / D_);
  float var = tq * (1.0f / D_) - mu * mu;
  float rstd = rsqrtf(var + 1e-5f);
  float4 gv = *(const float4*)(g  + t * 4);
  float4 bv = *(const float4*)(be + t * 4);
  ushort4v o;
  o[0] = f2b((v.x - mu) * rstd * gv.x + bv.x);
  o[1] = f2b((v.y - mu) * rstd * gv.y + bv.y);
  o[2] = f2b((v.z - mu) * rstd * gv.z + bv.z);
  o[3] = f2b((v.w - mu) * rstd * gv.w + bv.w);
  *(ushort4v*)(out + (size_t)row * D_ + t * 4) = o;
}

// ---------------- GEMM: C = A[M,K](bf16) @ Bt[N,K]^T (bf16), fp32 acc -----
// 128x128 tile, BK=32, 4 waves (2x2), global_load_lds staging.
// MODE: 0 = fused QKV scatter: C0=q[B,H,S,DK], C1=k[B,H,S,DK], C2=vT[B,H,DK,S]
//       1 = fp32 store: acc + bias + fp32 residual (C0)
//       2 = bf16 store: gelu(acc + bias) (C0)
template<int MODE>
__global__ __launch_bounds__(256) void gemm_bf16(
    const ushort* __restrict__ A, const ushort* __restrict__ Bt,
    void* __restrict__ C0, void* __restrict__ C1, void* __restrict__ C2,
    const float* __restrict__ bias, const float* __restrict__ resf,
    int M, int N, int K)
{
  __shared__ ushort As[128 * 32];
  __shared__ ushort Bs[128 * 32];
  int m0 = blockIdx.y * 128, n0 = blockIdx.x * 128;
  int t = threadIdx.x;
  int wv = t >> 6, lane = t & 63;
  int wr = wv >> 1, wc = wv & 1;
  int lg = lane >> 4, lr = lane & 15;
  int lrow = lane >> 2, lcol = (lane & 3) << 3;

  f32x4 acc[4][4];
  for (int i = 0; i < 4; i++)
    for (int j = 0; j < 4; j++) acc[i][j] = (f32x4){0.f, 0.f, 0.f, 0.f};

  int nkt = K >> 5;
  for (int kt = 0; kt < nkt; ++kt){
    __syncthreads();
    {
      const ushort* Ag = A  + (size_t)(m0 + wv * 16 + lrow) * K + (kt << 5) + lcol;
      const ushort* Bg = Bt + (size_t)(n0 + wv * 16 + lrow) * K + (kt << 5) + lcol;
      gload16(Ag,                    As + wv * 512);
      gload16(Ag + (size_t)64 * K,   As + 2048 + wv * 512);
      gload16(Bg,                    Bs + wv * 512);
      gload16(Bg + (size_t)64 * K,   Bs + 2048 + wv * 512);
    }
    __syncthreads();
    bf16x8 af[4], bfr[4];
    for (int i = 0; i < 4; i++)
      af[i]  = *(const bf16x8*)(As + (wr * 64 + i * 16 + lr) * 32 + lg * 8);
    for (int j = 0; j < 4; j++)
      bfr[j] = *(const bf16x8*)(Bs + (wc * 64 + j * 16 + lr) * 32 + lg * 8);
    for (int i = 0; i < 4; i++)
      for (int j = 0; j < 4; j++)
        acc[i][j] = mfma16(af[i], bfr[j], acc[i][j]);
  }

  for (int i = 0; i < 4; i++){
    int mb = m0 + wr * 64 + i * 16 + lg * 4;
    for (int j = 0; j < 4; j++){
      int ng = n0 + wc * 64 + j * 16 + lr;
      for (int r = 0; r < 4; r++){
        int mg = mb + r;
        float vacc = acc[i][j][r];
        if constexpr (MODE == 0){
          int b = mg >> 11, si = mg & 2047;
          int which = ng >> 10;
          int hh = (ng >> 6) & 15, dk = ng & 63;
          if (which == 0)
            ((ushort*)C0)[((((size_t)b * H_ + hh) * S_ + si) << 6) + dk] = f2b(vacc);
          else if (which == 1)
            ((ushort*)C1)[((((size_t)b * H_ + hh) * S_ + si) << 6) + dk] = f2b(vacc);
          else
            ((ushort*)C2)[((((size_t)b * H_ + hh) * DK_ + dk) << 11) + si] = f2b(vacc);
        } else if constexpr (MODE == 1){
          size_t idx = (size_t)mg * N + ng;
          ((float*)C0)[idx] = vacc + bias[ng] + resf[idx];
        } else {
          size_t idx = (size_t)mg * N + ng;
          float xv = vacc + bias[ng];
          float gel = xv * 0.5f * (1.0f + erff(xv * 0.70710678118f));
          ((ushort*)C0)[idx] = f2b(gel);
        }
      }
    }
  }
}

// ---------------- flash attention, causal, MFMA, LDS-staged K/V -----------
// grid (S/128, H, B), 256 thr = 4 waves; wave owns 32 q-rows (2 rowgroups).
// KV tiles of 64 keys staged in LDS (double-buffered, global_load_lds),
// XOR-swizzled (elem bits[3:5] ^= row&7) to kill ds_read_b128 bank conflicts.
// q,k: [B,H,S,DK] bf16; vT: [B,H,DK,S] bf16; out: [B*S, D] bf16 row-major.
#define KVB 64
__global__ __launch_bounds__(256) void attn_fwd(
    const ushort* __restrict__ qg, const ushort* __restrict__ kg,
    const ushort* __restrict__ vg, ushort* __restrict__ outp)
{
  int h = blockIdx.y, b = blockIdx.z;
  int wave = threadIdx.x >> 6, lane = threadIdx.x & 63;
  int lg = lane >> 4, lr = lane & 15;
  int q0 = blockIdx.x * 128;
  int qbase = q0 + wave * 32;
  const ushort* qp = qg + (((size_t)b * H_ + h) * S_) * DK_;
  const ushort* kp = kg + (((size_t)b * H_ + h) * S_) * DK_;
  const ushort* vp = vg + (((size_t)b * H_ + h) * DK_) * S_;

  __shared__ ushort Ks[2][KVB][64];      // rows = key, cols = dk   (8 KB x2)
  __shared__ ushort Vs[2][KVB][64];      // rows = dk,  cols = key  (8 KB x2)
  __shared__ ushort Ps[4][2][16][64];    // per-wave, per-rowgroup P (16 KB)

  bf16x8 aq[2][2];
#pragma unroll
  for (int rg = 0; rg < 2; rg++)
#pragma unroll
    for (int c = 0; c < 2; c++)
      aq[rg][c] = *(const bf16x8*)(qp + (size_t)(qbase + rg * 16 + lr) * DK_ + c * 32 + lg * 8);

  float m[2][4], l[2][4];
  f32x4 oacc[2][4];
#pragma unroll
  for (int rg = 0; rg < 2; rg++)
#pragma unroll
    for (int r = 0; r < 4; r++){ m[rg][r] = -3.0e38f; l[rg][r] = 0.f; }
#pragma unroll
  for (int rg = 0; rg < 2; rg++)
#pragma unroll
    for (int c = 0; c < 4; c++) oacc[rg][c] = (f32x4){0.f, 0.f, 0.f, 0.f};

  // staging lane map: 8 rows per gload; source col pre-swizzled so that the
  // linear LDS dest (base + lane*16) holds swizzled data
  int r8   = lane >> 3;
  int srcc = ((lane & 7) ^ r8) << 3;     // elems
  int swz  = (lr & 7) << 3;              // read-side XOR (elem bits 3..5)

  // prologue: stage tile 0 -> buf 0
#pragma unroll
  for (int j = 0; j < 2; j++){
    int rowb = wave * 16 + j * 8;
    gload16(kp + (size_t)(rowb + r8) * 64 + srcc,        &Ks[0][rowb][0]);
    gload16(vp + (size_t)(rowb + r8) * S_ + srcc,        &Vs[0][rowb][0]);
  }

  int nkt = q0 / KVB + 2;
  int cur = 0;
  for (int kt = 0; kt < nkt; ++kt){
    int kb = kt * KVB;
    __syncthreads();                       // drains stage of buf[cur]
    if (kt + 1 < nkt){
      int kb2 = kb + KVB;
#pragma unroll
      for (int j = 0; j < 2; j++){
        int rowb = wave * 16 + j * 8;
        gload16(kp + (size_t)(kb2 + rowb + r8) * 64 + srcc, &Ks[cur ^ 1][rowb][0]);
        gload16(vp + (size_t)(rowb + r8) * S_ + kb2 + srcc, &Vs[cur ^ 1][rowb][0]);
      }
    }
    // K / V fragments from LDS (shared by both rowgroups)
    bf16x8 bk[4][2], bv[4][2];
#pragma unroll
    for (int kk = 0; kk < 4; kk++)
#pragma unroll
      for (int c = 0; c < 2; c++)
        bk[kk][c] = *(const bf16x8*)&Ks[cur][kk * 16 + lr][(c * 32 + lg * 8) ^ swz];
#pragma unroll
    for (int c = 0; c < 4; c++)
#pragma unroll
      for (int c2 = 0; c2 < 2; c2++)
        bv[c][c2] = *(const bf16x8*)&Vs[cur][c * 16 + lr][(c2 * 32 + lg * 8) ^ swz];

#pragma unroll
    for (int rg = 0; rg < 2; rg++){
      f32x4 s[4];
#pragma unroll
      for (int kk = 0; kk < 4; kk++){
        f32x4 z = (f32x4){0.f, 0.f, 0.f, 0.f};
        s[kk] = mfma16(aq[rg][0], bk[kk][0], z);
        s[kk] = mfma16(aq[rg][1], bk[kk][1], s[kk]);
      }
      int qrow0 = qbase + rg * 16 + lg * 4;
      bool domask = (kb + KVB - 1) > qrow0;
#pragma unroll
      for (int kk = 0; kk < 4; kk++)
#pragma unroll
        for (int r = 0; r < 4; r++){
          float sv = s[kk][r] * 0.125f;    // 1/sqrt(64)
          if (domask && (kb + kk * 16 + lr) > (qrow0 + r)) sv = -1.0e30f;
          s[kk][r] = sv;
        }
      float p[4][4];
#pragma unroll
      for (int r = 0; r < 4; r++){
        float rm = fmaxf(fmaxf(s[0][r], s[1][r]), fmaxf(s[2][r], s[3][r]));
#pragma unroll
        for (int off = 1; off < 16; off <<= 1) rm = fmaxf(rm, __shfl_xor(rm, off));
        float mnew = fmaxf(m[rg][r], rm);
        float alpha = expf(m[rg][r] - mnew);
        float rs = 0.f;
#pragma unroll
        for (int kk = 0; kk < 4; kk++){
          p[kk][r] = expf(s[kk][r] - mnew);
          rs += p[kk][r];
        }
#pragma unroll
        for (int off = 1; off < 16; off <<= 1) rs += __shfl_xor(rs, off);
        l[rg][r] = l[rg][r] * alpha + rs;
        m[rg][r] = mnew;
#pragma unroll
        for (int c = 0; c < 4; c++) oacc[rg][c][r] *= alpha;
      }
      // P: D-layout -> LDS (swizzled) -> A-layout fragments
#pragma unroll
      for (int kk = 0; kk < 4; kk++)
#pragma unroll
        for (int r = 0; r < 4; r++){
          int prow = lg * 4 + r;
          Ps[wave][rg][prow][(kk * 16 + lr) ^ ((prow & 7) << 3)] = f2b(p[kk][r]);
        }
      bf16x8 pa0 = *(const bf16x8*)&Ps[wave][rg][lr][(lg * 8) ^ swz];
      bf16x8 pa1 = *(const bf16x8*)&Ps[wave][rg][lr][(32 + lg * 8) ^ swz];
#pragma unroll
      for (int c = 0; c < 4; c++){
        oacc[rg][c] = mfma16(pa0, bv[c][0], oacc[rg][c]);
        oacc[rg][c] = mfma16(pa1, bv[c][1], oacc[rg][c]);
      }
    }
    cur ^= 1;
  }
#pragma unroll
  for (int rg = 0; rg < 2; rg++)
#pragma unroll
    for (int c = 0; c < 4; c++)
#pragma unroll
      for (int r = 0; r < 4; r++){
        size_t row = (size_t)b * S_ + qbase + rg * 16 + lg * 4 + r;
        outp[row * D_ + h * DK_ + c * 16 + lr] = f2b(oacc[rg][c][r] / l[rg][r]);
      }
}

// --------------------------------------------------------------------------
extern "C" void kernel_launch(void* const* d_in, const int* in_sizes, int n_in,
                              void* d_out, int out_size, void* d_ws, size_t ws_size,
                              hipStream_t stream)
{
  const float* x   = (const float*)d_in[0];
  const float* wq  = (const float*)d_in[1];
  const float* wk  = (const float*)d_in[2];
  const float* wv  = (const float*)d_in[3];
  const float* wo  = (const float*)d_in[4];
  const float* bo  = (const float*)d_in[5];
  const float* w1  = (const float*)d_in[6];
  const float* b1  = (const float*)d_in[7];
  const float* w2  = (const float*)d_in[8];
  const float* b2  = (const float*)d_in[9];
  const float* g1  = (const float*)d_in[10];
  const float* be1 = (const float*)d_in[11];
  const float* g2  = (const float*)d_in[12];
  const float* be2 = (const float*)d_in[13];

  char* ws = (char*)d_ws;
  const size_t MB = 1ull << 20;
  ushort* wqkvT = (ushort*)(ws + 0 * MB);  // 6 MiB [3072][1024]
  ushort* woT  = (ushort*)(ws + 6 * MB);   // 2 MiB
  ushort* w1T  = (ushort*)(ws + 8 * MB);   // 8 MiB  [4096][1024]
  ushort* w2T  = (ushort*)(ws + 16 * MB);  // 8 MiB  [1024][4096]
  ushort* hbuf = (ushort*)(ws + 24 * MB);  // 16 MiB: LN1 out -> attn out
  ushort* qbuf = (ushort*)(ws + 40 * MB);  // 16 MiB: Q [B,H,S,DK]
  ushort* kbuf = (ushort*)(ws + 56 * MB);  // 16 MiB: K [B,H,S,DK] -> h2
  ushort* vbuf = (ushort*)(ws + 72 * MB);  // 16 MiB: V [B,H,DK,S]
  float*  x2f  = (float*)(ws + 88 * MB);   // 32 MiB: post-attn residual (fp32)
  ushort* a1   = (ushort*)(ws + 120 * MB); // 64 MiB: ff1 out [8192][4096]
  // total 184 MiB

  dim3 tb(32, 8);
  transpose_f32_bf16<<<dim3(32, 32), tb, 0, stream>>>(wq, wqkvT, 1024, 1024);
  transpose_f32_bf16<<<dim3(32, 32), tb, 0, stream>>>(wk, wqkvT + (1024ull*1024), 1024, 1024);
  transpose_f32_bf16<<<dim3(32, 32), tb, 0, stream>>>(wv, wqkvT + (2048ull*1024), 1024, 1024);
  transpose_f32_bf16<<<dim3(32, 32), tb, 0, stream>>>(wo, woT, 1024, 1024);
  transpose_f32_bf16<<<dim3(128, 32), tb, 0, stream>>>(w1, w1T, 1024, 4096);
  transpose_f32_bf16<<<dim3(32, 128), tb, 0, stream>>>(w2, w2T, 4096, 1024);

  ln_f32<<<8192, 256, 0, stream>>>(x, g1, be1, hbuf);

  // fused QKV: [8192,1024] @ [3072,1024]^T, scatter epilogue
  gemm_bf16<0><<<dim3(24, 64), 256, 0, stream>>>(hbuf, wqkvT, qbuf, kbuf, vbuf,
                                                 nullptr, nullptr, 8192, 3072, 1024);

  attn_fwd<<<dim3(16, 16, 4), 256, 0, stream>>>(qbuf, kbuf, vbuf, hbuf);

  // x2 = attn@wo + bo + x   (fp32)
  gemm_bf16<1><<<dim3(8, 64), 256, 0, stream>>>(hbuf, woT, x2f, nullptr, nullptr,
                                                bo, x, 8192, 1024, 1024);

  ln_f32<<<8192, 256, 0, stream>>>(x2f, g2, be2, kbuf);  // h2 into kbuf

  // feedforward, full M=8192 (no chunking)
  gemm_bf16<2><<<dim3(32, 64), 256, 0, stream>>>(kbuf, w1T, a1, nullptr, nullptr,
                                                 b1, nullptr, 8192, 4096, 1024);
  gemm_bf16<1><<<dim3(8, 64), 256, 0, stream>>>(a1, w2T, d_out, nullptr, nullptr,
                                                b2, x2f, 8192, 1024, 4096);
}